// Round 1
// baseline (12055.556 us; speedup 1.0000x reference)
//
#include <hip/hip_runtime.h>

typedef unsigned short u16;
typedef unsigned int   u32;
typedef __attribute__((ext_vector_type(8))) short bh8;   // 8 bf16 (4 VGPRs) — MFMA A/B frag
typedef __attribute__((ext_vector_type(4))) float f4;    // MFMA C/D frag

#define HH   512
#define DIN  32
#define NB   256
#define GB   8      // batch groups
#define GC   32     // col groups
#define BM   32     // rows per block
#define HC   16     // h-cols per block (=> 64 gate cols per block, 16 per wave/gate-type)
#define KC   256    // K chunk staged in LDS
#define LDA  264    // padded LDS leading dim (ushorts): stride 528B -> 2-way max conflict

__device__ __forceinline__ u16 bf16_rne(float f){
  u32 u = __float_as_uint(f);
  u32 r = (u + 0x7FFFu + ((u >> 16) & 1u)) >> 16;
  return (u16)r;
}
__device__ __forceinline__ float bf16f(u16 h){ return __uint_as_float(((u32)h) << 16); }
__device__ __forceinline__ float sig_(float x){ return 1.0f/(1.0f + __expf(-x)); }
__device__ __forceinline__ float tanh_(float x){ float e = __expf(2.0f*x); return 1.0f - 2.0f/(e + 1.0f); }

// ---------------- prologue kernels ----------------

__global__ void split_kernel(const float* __restrict__ src, u16* __restrict__ hi,
                             u16* __restrict__ lo, int n){
  int i = blockIdx.x*256 + threadIdx.x;
  if (i < n){
    float f = src[i];
    u16 h = bf16_rne(f);
    hi[i] = h;
    lo[i] = bf16_rne(f - bf16f(h));
  }
}

// W_comb = Whh_d + Wih_d @ Wl   ([4H,H]), split to bf16 hi/lo
__global__ void comb_kernel(const float* __restrict__ WhhD, const float* __restrict__ WihD,
                            const float* __restrict__ Wl, u16* __restrict__ hi, u16* __restrict__ lo){
  int idx = blockIdx.x*256 + threadIdx.x;
  if (idx >= 4*HH*HH) return;
  int r = idx >> 9;      // gate row 0..2047
  int c = idx & 511;     // h col
  float acc = WhhD[idx];
  #pragma unroll
  for (int j=0;j<DIN;j++) acc += WihD[r*DIN + j] * Wl[j*HH + c];
  u16 h = bf16_rne(acc);
  hi[idx] = h;
  lo[idx] = bf16_rne(acc - bf16f(h));
}

// b_comb = b_d + Wih_d @ bl
__global__ void bcomb_kernel(const float* __restrict__ bD, const float* __restrict__ WihD,
                             const float* __restrict__ bl, float* __restrict__ bc){
  int r = blockIdx.x*256 + threadIdx.x;
  if (r >= 4*HH) return;
  float acc = bD[r];
  #pragma unroll
  for (int j=0;j<DIN;j++) acc += WihD[r*DIN + j] * bl[j];
  bc[r] = acc;
}

// final y reduce for last decoder step
__global__ void yfinal_kernel(const float* __restrict__ ypIn, const float* __restrict__ blv,
                              float* __restrict__ yOut){
  int idx = blockIdx.x*256 + threadIdx.x;
  if (idx >= NB*DIN) return;
  int row = idx >> 5;
  int d   = idx & 31;
  int bi  = row >> 5;
  int r   = row & 31;
  float acc = blv[d];
  #pragma unroll
  for (int c=0;c<GC;c++)
    acc += ypIn[(size_t)bi*(GC*BM*DIN) + (size_t)c*(BM*DIN) + (size_t)r*DIN + d];
  yOut[(size_t)row*DIN + d] = acc;
}

// ---------------- the per-step kernel ----------------
// grid = 256 blocks (bi = blk>>5 batch group, cj = blk&31 h-col group), 256 threads (4 waves).
// Wave w computes gate-type w tile [32 rows x 16 cols] with bf16 split-3 MFMA.
// h staged in LDS (hi+lo), K-chunked; W hi/lo frags streamed from global (L2-resident).
__global__ __launch_bounds__(256) void lstm_step(
    const u16* __restrict__ Whi, const u16* __restrict__ Wlo,     // [2048][512] bf16 hi/lo
    const float* __restrict__ bias,                               // [2048]
    const u16* __restrict__ WihHi, const u16* __restrict__ WihLo, // [2048][32] or null
    const float* __restrict__ Xt,                                 // [256][32] or null
    const u16* __restrict__ hinHi, const u16* __restrict__ hinLo, // [256][512]
    u16* __restrict__ houtHi, u16* __restrict__ houtLo,
    float* __restrict__ cbuf,                                     // [256][512]
    const float* __restrict__ Wl,                                 // [32][512] or null
    float* __restrict__ ypOut,                                    // [8][32][32][32] or null
    const float* __restrict__ ypIn,                               // prev step partials or null
    const float* __restrict__ blv,                                // bl or null
    float* __restrict__ yOut)                                     // d_out slice or null
{
  __shared__ u16 Ahi[BM][LDA];
  __shared__ u16 Alo[BM][LDA];
  __shared__ float gLds[4][BM][HC+1];
  __shared__ float hT[BM][HC+1];

  const int tid = threadIdx.x;
  const int w   = tid >> 6;
  const int l   = tid & 63;
  const int bi  = blockIdx.x >> 5;
  const int cj  = blockIdx.x & 31;
  const int r0  = bi*BM;
  const int hc0 = cj*HC;
  const int l15 = l & 15;
  const int lk  = l >> 4;

  // ---- reduce previous decoder step's y partials -> d_out[t-1] ----
  if (ypIn != nullptr && tid < DIN) {
    float acc = blv[tid];
    const float* pp = ypIn + (size_t)bi*(GC*BM*DIN) + (size_t)cj*DIN + tid;
    #pragma unroll
    for (int c=0;c<GC;c++) acc += pp[(size_t)c*(BM*DIN)];
    yOut[(size_t)(r0 + cj)*DIN + tid] = acc;
  }

  f4 ac[2][3];
  #pragma unroll
  for (int m=0;m<2;m++)
    #pragma unroll
    for (int q=0;q<3;q++) ac[m][q] = (f4){0.f,0.f,0.f,0.f};

  const int gcol = w*HH + hc0 + l15;   // this lane's gate column (= W row)

  // ---- encoder input term: x @ Wih.T (K=32), split-3 ----
  if (Xt != nullptr) {
    const int kof = lk*8;
    bh8 bh  = *(const bh8*)(WihHi + (size_t)gcol*DIN + kof);
    bh8 blo = *(const bh8*)(WihLo + (size_t)gcol*DIN + kof);
    #pragma unroll
    for (int m=0;m<2;m++){
      const float* xp = Xt + (size_t)(r0 + m*16 + l15)*DIN + kof;
      f4 xa = *(const f4*)xp;
      f4 xb = *(const f4*)(xp+4);
      bh8 ah, al;
      #pragma unroll
      for (int j=0;j<4;j++){
        u16 h1 = bf16_rne(xa[j]); ah[j]   = (short)h1; al[j]   = (short)bf16_rne(xa[j] - bf16f(h1));
        u16 h2 = bf16_rne(xb[j]); ah[4+j] = (short)h2; al[4+j] = (short)bf16_rne(xb[j] - bf16f(h2));
      }
      ac[m][0] = __builtin_amdgcn_mfma_f32_16x16x32_bf16(ah, bh,  ac[m][0], 0,0,0);
      ac[m][1] = __builtin_amdgcn_mfma_f32_16x16x32_bf16(al, bh,  ac[m][1], 0,0,0);
      ac[m][2] = __builtin_amdgcn_mfma_f32_16x16x32_bf16(ah, blo, ac[m][2], 0,0,0);
    }
  }

  const u16* wrow_hi = Whi + (size_t)gcol*HH;
  const u16* wrow_lo = Wlo + (size_t)gcol*HH;

  // ---- main recurrence matmul: gates += h @ Whh.T, split-3, K chunked ----
  #pragma unroll
  for (int ch=0; ch<2; ch++){
    __syncthreads();
    {
      const int base = ch*KC;
      for (int i=tid; i < BM*(KC/8); i += 256){
        int row = i >> 5;
        int c16 = i & 31;
        *(uint4*)&Ahi[row][c16*8] = *(const uint4*)(hinHi + (size_t)(r0+row)*HH + base + c16*8);
        *(uint4*)&Alo[row][c16*8] = *(const uint4*)(hinLo + (size_t)(r0+row)*HH + base + c16*8);
      }
    }
    __syncthreads();
    #pragma unroll
    for (int ks=0; ks<8; ks++){
      const int kof = ks*32 + lk*8;
      bh8 a0h = *(const bh8*)&Ahi[l15][kof];
      bh8 a0l = *(const bh8*)&Alo[l15][kof];
      bh8 a1h = *(const bh8*)&Ahi[16+l15][kof];
      bh8 a1l = *(const bh8*)&Alo[16+l15][kof];
      const int gk = ch*KC + kof;
      bh8 bh  = *(const bh8*)(wrow_hi + gk);
      bh8 blo = *(const bh8*)(wrow_lo + gk);
      ac[0][0] = __builtin_amdgcn_mfma_f32_16x16x32_bf16(a0h, bh,  ac[0][0], 0,0,0);
      ac[1][0] = __builtin_amdgcn_mfma_f32_16x16x32_bf16(a1h, bh,  ac[1][0], 0,0,0);
      ac[0][1] = __builtin_amdgcn_mfma_f32_16x16x32_bf16(a0l, bh,  ac[0][1], 0,0,0);
      ac[1][1] = __builtin_amdgcn_mfma_f32_16x16x32_bf16(a1l, bh,  ac[1][1], 0,0,0);
      ac[0][2] = __builtin_amdgcn_mfma_f32_16x16x32_bf16(a0h, blo, ac[0][2], 0,0,0);
      ac[1][2] = __builtin_amdgcn_mfma_f32_16x16x32_bf16(a1h, blo, ac[1][2], 0,0,0);
    }
  }

  // ---- write gates to LDS (C/D layout: col=lane&15, row=(lane>>4)*4+reg) ----
  #pragma unroll
  for (int m=0;m<2;m++){
    f4 s = ac[m][0];
    #pragma unroll
    for (int r=0;r<4;r++) s[r] = s[r] + ac[m][1][r] + ac[m][2][r];
    #pragma unroll
    for (int r=0;r<4;r++) gLds[w][m*16 + lk*4 + r][l15] = s[r];
  }
  __syncthreads();

  // ---- elementwise LSTM cell update: 2 elems/thread ----
  #pragma unroll
  for (int e=0;e<2;e++){
    int idx = tid*2 + e;
    int row = idx >> 4;
    int col = idx & 15;
    float gi = gLds[0][row][col] + bias[0*HH + hc0 + col];
    float gf = gLds[1][row][col] + bias[1*HH + hc0 + col];
    float gg = gLds[2][row][col] + bias[2*HH + hc0 + col];
    float go = gLds[3][row][col] + bias[3*HH + hc0 + col];
    float iv = sig_(gi), fv = sig_(gf), gv = tanh_(gg), ov = sig_(go);
    size_t cofs = (size_t)(r0+row)*HH + hc0 + col;
    float cv = fv*cbuf[cofs] + iv*gv;
    cbuf[cofs] = cv;
    float hn = ov*tanh_(cv);
    u16 hh = bf16_rne(hn);
    houtHi[cofs] = hh;
    houtLo[cofs] = bf16_rne(hn - bf16f(hh));
    if (ypOut) hT[row][col] = hn;
  }

  // ---- y partials (decoder): ypOut[bi][cj][r][d] = sum_c hT[r][c]*Wl[d][hc0+c] ----
  if (ypOut != nullptr){
    __syncthreads();
    #pragma unroll
    for (int e=0;e<4;e++){
      int idx = tid*4 + e;
      int r = idx >> 5;
      int d = idx & 31;
      float acc = 0.f;
      #pragma unroll
      for (int c=0;c<HC;c++) acc += hT[r][c] * Wl[(size_t)d*HH + hc0 + c];
      ypOut[(size_t)((bi*GC + cj)*BM + r)*DIN + d] = acc;
    }
  }
}

// ---------------- host ----------------

extern "C" void kernel_launch(void* const* d_in, const int* in_sizes, int n_in,
                              void* d_out, int out_size, void* d_ws, size_t ws_size,
                              hipStream_t stream) {
  (void)in_sizes; (void)n_in; (void)out_size; (void)ws_size;
  const float* X    = (const float*)d_in[0];
  const float* WihE = (const float*)d_in[1];
  const float* WhhE = (const float*)d_in[2];
  const float* bE   = (const float*)d_in[3];
  const float* WihD = (const float*)d_in[4];
  const float* WhhD = (const float*)d_in[5];
  const float* bD   = (const float*)d_in[6];
  const float* Wl   = (const float*)d_in[7];
  const float* bl   = (const float*)d_in[8];
  float* out = (float*)d_out;

  char* p = (char*)d_ws;
  auto alloc = [&](size_t bytes)->char* {
    char* r = p; p += (bytes + 255) & ~(size_t)255; return r;
  };
  const size_t WN = (size_t)4*HH*HH;        // 1,048,576
  u16* WhhE_hi = (u16*)alloc(WN*2);
  u16* WhhE_lo = (u16*)alloc(WN*2);
  u16* WhhD_hi = (u16*)alloc(WN*2);
  u16* WhhD_lo = (u16*)alloc(WN*2);
  u16* Wc_hi   = (u16*)alloc(WN*2);
  u16* Wc_lo   = (u16*)alloc(WN*2);
  u16* WihE_hi = (u16*)alloc((size_t)4*HH*DIN*2);
  u16* WihE_lo = (u16*)alloc((size_t)4*HH*DIN*2);
  float* bcomb = (float*)alloc((size_t)4*HH*4);
  u16* hHi[2], *hLo[2];
  hHi[0] = (u16*)alloc((size_t)NB*HH*2);
  hLo[0] = (u16*)alloc((size_t)NB*HH*2);
  hHi[1] = (u16*)alloc((size_t)NB*HH*2);
  hLo[1] = (u16*)alloc((size_t)NB*HH*2);
  float* cbuf = (float*)alloc((size_t)NB*HH*4);
  float* yp[2];
  yp[0] = (float*)alloc((size_t)GB*GC*BM*DIN*4);
  yp[1] = (float*)alloc((size_t)GB*GC*BM*DIN*4);

  hipMemsetAsync(cbuf,   0, (size_t)NB*HH*4, stream);
  hipMemsetAsync(hHi[0], 0, (size_t)NB*HH*2, stream);
  hipMemsetAsync(hLo[0], 0, (size_t)NB*HH*2, stream);

  split_kernel<<<(int)((WN+255)/256), 256, 0, stream>>>(WhhE, WhhE_hi, WhhE_lo, (int)WN);
  split_kernel<<<(int)((WN+255)/256), 256, 0, stream>>>(WhhD, WhhD_hi, WhhD_lo, (int)WN);
  split_kernel<<<(4*HH*DIN+255)/256, 256, 0, stream>>>(WihE, WihE_hi, WihE_lo, 4*HH*DIN);
  comb_kernel<<<(int)((WN+255)/256), 256, 0, stream>>>(WhhD, WihD, Wl, Wc_hi, Wc_lo);
  bcomb_kernel<<<(4*HH+255)/256, 256, 0, stream>>>(bD, WihD, bl, bcomb);

  int cur = 0;
  // encoder
  for (int t=0; t<512; t++){
    lstm_step<<<256, 256, 0, stream>>>(WhhE_hi, WhhE_lo, bE, WihE_hi, WihE_lo,
        X + (size_t)t*NB*DIN, hHi[cur], hLo[cur], hHi[cur^1], hLo[cur^1], cbuf,
        nullptr, nullptr, nullptr, nullptr, nullptr);
    cur ^= 1;
  }
  // decoder step 0 (x = 0): raw Whh_d / b_d, emit y partials
  lstm_step<<<256, 256, 0, stream>>>(WhhD_hi, WhhD_lo, bD, nullptr, nullptr, nullptr,
      hHi[cur], hLo[cur], hHi[cur^1], hLo[cur^1], cbuf,
      Wl, yp[0], nullptr, nullptr, nullptr);
  cur ^= 1;
  // decoder steps 1..511: combined weights; each reduces previous step's y partials
  for (int s=1; s<512; s++){
    lstm_step<<<256, 256, 0, stream>>>(Wc_hi, Wc_lo, bcomb, nullptr, nullptr, nullptr,
        hHi[cur], hLo[cur], hHi[cur^1], hLo[cur^1], cbuf,
        Wl, yp[s&1], yp[(s&1)^1], bl, out + (size_t)(s-1)*NB*DIN);
    cur ^= 1;
  }
  yfinal_kernel<<<(NB*DIN+255)/256, 256, 0, stream>>>(yp[1], bl, out + (size_t)511*NB*DIN);
}

// Round 3
// 5184.990 us; speedup vs baseline: 2.3251x; 2.3251x over previous
//
#include <hip/hip_runtime.h>

typedef unsigned short u16;
typedef unsigned int   u32;
typedef __attribute__((ext_vector_type(8))) short bh8;   // 8 bf16 — MFMA A/B frag
typedef __attribute__((ext_vector_type(4))) float f4;    // MFMA C/D frag
typedef __attribute__((ext_vector_type(4))) u32  u32x4;  // 16B staging temp

#define HH    512
#define DIN   32
#define NB    256
#define GB    8      // batch groups (blocks sharing h)
#define GC    32     // col groups per batch group
#define BM    32     // batch rows per block
#define HC    16     // h-cols per block
#define KC    256    // K chunk staged in LDS
#define LDA   264    // padded LDS leading dim (u16): stride 528B
#define NSTEP 1024

__device__ __forceinline__ u16 bf16_rne(float f){
  u32 u = __float_as_uint(f);
  return (u16)((u + 0x7FFFu + ((u >> 16) & 1u)) >> 16);
}
__device__ __forceinline__ float bf16f(u16 h){ return __uint_as_float(((u32)h) << 16); }
__device__ __forceinline__ float sig_(float x){ return 1.0f/(1.0f + __expf(-x)); }
__device__ __forceinline__ float tanh_(float x){ float e = __expf(2.0f*x); return 1.0f - 2.0f/(e + 1.0f); }

// ---- MALL-coherent (sc0 sc1) and plain asm memory ops -----------------------
__device__ __forceinline__ u32x4 ld16u_cg(const void* p){
  u32x4 r; asm volatile("global_load_dwordx4 %0, %1, off sc0 sc1" : "=v"(r) : "v"(p)); return r;
}
__device__ __forceinline__ bh8 ld16b_nc(const void* p){
  bh8 r; asm volatile("global_load_dwordx4 %0, %1, off" : "=v"(r) : "v"(p)); return r;
}
__device__ __forceinline__ float ld4f_cg(const void* p){
  float r; asm volatile("global_load_dword %0, %1, off sc0 sc1" : "=v"(r) : "v"(p)); return r;
}
__device__ __forceinline__ void st4_cg(void* p, u32 v){
  asm volatile("global_store_dword %0, %1, off sc0 sc1" :: "v"(p), "v"(v) : "memory");
}
__device__ __forceinline__ void st16f_cg(void* p, f4 v){
  asm volatile("global_store_dwordx4 %0, %1, off sc0 sc1" :: "v"(p), "v"(v) : "memory");
}
__device__ __forceinline__ void st4f_nc(void* p, float v){
  asm volatile("global_store_dword %0, %1, off" :: "v"(p), "v"(v) : "memory");
}
__device__ __forceinline__ void vm_wait0(){ asm volatile("s_waitcnt vmcnt(0)" ::: "memory"); }
__device__ __forceinline__ void vm_wait8(){ asm volatile("s_waitcnt vmcnt(8)" ::: "memory"); }
#define SB0() __builtin_amdgcn_sched_barrier(0)

// ---------------- prologue kernels ----------------
__global__ void split_kernel(const float* __restrict__ src, u16* __restrict__ hi,
                             u16* __restrict__ lo, int n){
  int i = blockIdx.x*256 + threadIdx.x;
  if (i < n){
    float f = src[i];
    u16 h = bf16_rne(f);
    hi[i] = h;
    lo[i] = bf16_rne(f - bf16f(h));
  }
}

__global__ void comb_kernel(const float* __restrict__ WhhD, const float* __restrict__ WihD,
                            const float* __restrict__ Wl, u16* __restrict__ hi, u16* __restrict__ lo){
  int idx = blockIdx.x*256 + threadIdx.x;
  if (idx >= 4*HH*HH) return;
  int r = idx >> 9;
  int c = idx & 511;
  float acc = WhhD[idx];
  #pragma unroll
  for (int j=0;j<DIN;j++) acc += WihD[r*DIN + j] * Wl[j*HH + c];
  u16 h = bf16_rne(acc);
  hi[idx] = h;
  lo[idx] = bf16_rne(acc - bf16f(h));
}

__global__ void bcomb_kernel(const float* __restrict__ bD, const float* __restrict__ WihD,
                             const float* __restrict__ bl, float* __restrict__ bc){
  int r = blockIdx.x*256 + threadIdx.x;
  if (r >= 4*HH) return;
  float acc = bD[r];
  #pragma unroll
  for (int j=0;j<DIN;j++) acc += WihD[r*DIN + j] * bl[j];
  bc[r] = acc;
}

// ---------------- persistent kernel ----------------
struct PP {
  const u16 *WEhi, *WElo;
  const u16 *WXhi, *WXlo;
  const float *bE;
  const u16 *WDhi, *WDlo;
  const float *bD;
  const u16 *WChi, *WClo;
  const float *bC;
  const float *X;
  const float *Wl;
  const float *bl;
  u16 *hHi0, *hLo0, *hHi1, *hLo1;
  float *yp0, *yp1;
  float *out;
  u32 *cnt;           // [8][1024] monotonic per-(group,step) counters, pre-zeroed
};

// group barrier: no cache-maintenance fences — all cross-block data uses sc0sc1 ops,
// so only the counter (agent-scope atomic, MALL-coherent) needs ordering, provided
// by vmcnt(0)+s_barrier before the bump.
__device__ __forceinline__ void grp_barrier(u32* c, u32 n, int tid){
  vm_wait0();
  __syncthreads();
  if (tid == 0){
    __hip_atomic_fetch_add(c, 1u, __ATOMIC_RELAXED, __HIP_MEMORY_SCOPE_AGENT);
    u32 v;
    do {
      __builtin_amdgcn_s_sleep(2);
      v = __hip_atomic_load(c, __ATOMIC_RELAXED, __HIP_MEMORY_SCOPE_AGENT);
    } while (v < n);
  }
  __syncthreads();
}

template<int MODE>
__device__ __forceinline__ void mfma_chunk(
    int ch, const u16 (&Ahi)[BM][LDA], const u16 (&Alo)[BM][LDA],
    const bh8 (&wh)[16], const bh8 (&wl)[16],
    const u16* wsh, const u16* wsl,
    f4 (&ac)[2][3], int l15, int lk)
{
  #pragma unroll
  for (int ks=0; ks<8; ks++){
    const int kof = ks*32 + lk*8;
    bh8 a0h = *(const bh8*)&Ahi[l15][kof];
    bh8 a0l = *(const bh8*)&Alo[l15][kof];
    bh8 a1h = *(const bh8*)&Ahi[16+l15][kof];
    bh8 a1l = *(const bh8*)&Alo[16+l15][kof];
    bh8 bhf, blf;
    if (MODE==1){
      bhf = ld16b_nc(wsh + ch*KC + kof);
      blf = ld16b_nc(wsl + ch*KC + kof);
      vm_wait0(); SB0();
    } else {
      bhf = wh[ch*8+ks];
      blf = wl[ch*8+ks];
    }
    ac[0][0] = __builtin_amdgcn_mfma_f32_16x16x32_bf16(a0h, bhf, ac[0][0], 0,0,0);
    ac[1][0] = __builtin_amdgcn_mfma_f32_16x16x32_bf16(a1h, bhf, ac[1][0], 0,0,0);
    ac[0][1] = __builtin_amdgcn_mfma_f32_16x16x32_bf16(a0l, bhf, ac[0][1], 0,0,0);
    ac[1][1] = __builtin_amdgcn_mfma_f32_16x16x32_bf16(a1l, bhf, ac[1][1], 0,0,0);
    ac[0][2] = __builtin_amdgcn_mfma_f32_16x16x32_bf16(a0h, blf, ac[0][2], 0,0,0);
    ac[1][2] = __builtin_amdgcn_mfma_f32_16x16x32_bf16(a1h, blf, ac[1][2], 0,0,0);
  }
}

// MODE: 0 = encoder, 1 = dec step0 (stream raw WhhD), 2 = decoder (reg W_comb)
template<int MODE>
__device__ __forceinline__ void dstep(
    const PP& p, int g,
    const bh8 (&wh)[16], const bh8 (&wl)[16], const bh8& wxh, const bh8& wxl,
    const float (&bv)[4][2], float blv,
    float (&cre)[2],
    u16 (&Ahi)[BM][LDA], u16 (&Alo)[BM][LDA],
    float (&gLds)[4][BM][HC+1], float (&hT)[BM][HC+1], float (&wlS)[DIN][HC+1],
    int tid, int w, int l15, int lk, int bi, int cj, int r0, int hc0, int gcol)
{
  const int wrb = g & 1, rdb = wrb ^ 1;
  const u16* hinHi = rdb ? p.hHi1 : p.hHi0;
  const u16* hinLo = rdb ? p.hLo1 : p.hLo0;
  u16* houtHi = wrb ? p.hHi1 : p.hHi0;
  u16* houtLo = wrb ? p.hLo1 : p.hLo0;

  // ---- reduce previous decoder step's y partials -> out[g-513] ----
  if (MODE==2 && tid < DIN){
    const float* ypIn = rdb ? p.yp1 : p.yp0;
    const float* q = ypIn + (size_t)bi*(GC*BM*DIN) + (size_t)cj*DIN + tid;
    float t[GC];
    #pragma unroll
    for (int c2=0;c2<GC;c2++) t[c2] = ld4f_cg(q + (size_t)c2*(BM*DIN));
    vm_wait0(); SB0();
    float acc = blv;
    #pragma unroll
    for (int c2=0;c2<GC;c2++) acc += t[c2];
    st4f_nc(p.out + (size_t)(g-513)*(NB*DIN) + (size_t)(r0+cj)*DIN + tid, acc);
  }

  f4 ac[2][3];
  #pragma unroll
  for (int m=0;m<2;m++)
    #pragma unroll
    for (int q2=0;q2<3;q2++) ac[m][q2] = (f4){0.f,0.f,0.f,0.f};

  // ---- encoder input term: x @ Wih.T (K=32), split-3 ----
  if (MODE==0){
    const float* Xt = p.X + (size_t)g*(NB*DIN);
    const int kof = lk*8;
    #pragma unroll
    for (int m=0;m<2;m++){
      const float* xp = Xt + (size_t)(r0 + m*16 + l15)*DIN + kof;
      f4 xa = *(const f4*)xp;
      f4 xb = *(const f4*)(xp+4);
      bh8 ah, al;
      #pragma unroll
      for (int j=0;j<4;j++){
        u16 h1 = bf16_rne(xa[j]); ah[j]   = (short)h1; al[j]   = (short)bf16_rne(xa[j] - bf16f(h1));
        u16 h2 = bf16_rne(xb[j]); ah[4+j] = (short)h2; al[4+j] = (short)bf16_rne(xb[j] - bf16f(h2));
      }
      ac[m][0] = __builtin_amdgcn_mfma_f32_16x16x32_bf16(ah, wxh, ac[m][0], 0,0,0);
      ac[m][1] = __builtin_amdgcn_mfma_f32_16x16x32_bf16(al, wxh, ac[m][1], 0,0,0);
      ac[m][2] = __builtin_amdgcn_mfma_f32_16x16x32_bf16(ah, wxl, ac[m][2], 0,0,0);
    }
    SB0();    // keep compiler X-loads + their waits entirely before the counted staging
  }

  // ---- coherent h staging: issue all 16 loads, then counted-vmcnt pipeline ----
  const u16* hb = hinHi + (size_t)r0*HH;
  const u16* lb = hinLo + (size_t)r0*HH;
  u32x4 tH[2][4], tL[2][4];
  #pragma unroll
  for (int ch=0; ch<2; ch++){
    #pragma unroll
    for (int j=0;j<4;j++){
      int i = tid + j*256; int row = i >> 5, c16 = i & 31;
      tH[ch][j] = ld16u_cg(hb + (size_t)row*HH + ch*KC + c16*8);
    }
    #pragma unroll
    for (int j=0;j<4;j++){
      int i = tid + j*256; int row = i >> 5, c16 = i & 31;
      tL[ch][j] = ld16u_cg(lb + (size_t)row*HH + ch*KC + c16*8);
    }
  }
  vm_wait8(); SB0();                      // chunk-0's 8 loads complete
  #pragma unroll
  for (int j=0;j<4;j++){
    int i = tid + j*256; int row = i >> 5, c16 = i & 31;
    *(u32x4*)&Ahi[row][c16*8] = tH[0][j];
    *(u32x4*)&Alo[row][c16*8] = tL[0][j];
  }
  __syncthreads();
  {
    const u16* wsh = (MODE==1) ? p.WDhi + (size_t)gcol*HH : nullptr;
    const u16* wsl = (MODE==1) ? p.WDlo + (size_t)gcol*HH : nullptr;
    mfma_chunk<MODE>(0, Ahi, Alo, wh, wl, wsh, wsl, ac, l15, lk);
    __syncthreads();
    vm_wait0(); SB0();                    // chunk-1 loads complete
    #pragma unroll
    for (int j=0;j<4;j++){
      int i = tid + j*256; int row = i >> 5, c16 = i & 31;
      *(u32x4*)&Ahi[row][c16*8] = tH[1][j];
      *(u32x4*)&Alo[row][c16*8] = tL[1][j];
    }
    __syncthreads();
    mfma_chunk<MODE>(1, Ahi, Alo, wh, wl, wsh, wsl, ac, l15, lk);
  }

  // ---- gates -> LDS (C/D layout: col=lane&15, row=(lane>>4)*4+reg) ----
  #pragma unroll
  for (int m=0;m<2;m++){
    f4 s = ac[m][0];
    #pragma unroll
    for (int r=0;r<4;r++) s[r] = s[r] + ac[m][1][r] + ac[m][2][r];
    #pragma unroll
    for (int r=0;r<4;r++) gLds[w][m*16 + lk*4 + r][l15] = s[r];
  }
  __syncthreads();

  // ---- elementwise cell update; c in registers; h-out via coherent stores ----
  {
    int idx0 = tid*2;
    int row = idx0 >> 4;
    int col0 = idx0 & 15;
    float hi2[2], lo2[2];
    #pragma unroll
    for (int e=0;e<2;e++){
      int col = col0 + e;
      float gi = gLds[0][row][col] + bv[0][e];
      float gf = gLds[1][row][col] + bv[1][e];
      float gg = gLds[2][row][col] + bv[2][e];
      float go = gLds[3][row][col] + bv[3][e];
      float iv = sig_(gi), fv = sig_(gf), gv = tanh_(gg), ov = sig_(go);
      float cv = fv*cre[e] + iv*gv;
      cre[e] = cv;
      float hn = ov*tanh_(cv);
      u16 hv = bf16_rne(hn);
      hi2[e] = (float)0;  // placeholder to keep structure clear
      hi2[e] = hn;        // hn kept for hT
      lo2[e] = bf16f(hv); // re-derive below
      (void)lo2;
      if (MODE>=1) hT[row][col] = hn;
      // pack handled after loop via recompute-free path:
      hi2[e] = __uint_as_float(((u32)bf16_rne(hn)) | ((u32)0));
      lo2[e] = hn;
    }
    // pack the two adjacent columns into one dword per buffer
    u16 h0 = bf16_rne(lo2[0]), h1 = bf16_rne(lo2[1]);
    u32 hp = (u32)h0 | ((u32)h1 << 16);
    u32 lp = (u32)bf16_rne(lo2[0] - bf16f(h0)) | ((u32)bf16_rne(lo2[1] - bf16f(h1)) << 16);
    size_t cofs = (size_t)(r0+row)*HH + hc0 + col0;
    st4_cg(houtHi + cofs, hp);
    st4_cg(houtLo + cofs, lp);
  }

  // ---- y partials (decoder): ypOut[bi][cj][r][d0..d0+3] ----
  if (MODE>=1){
    __syncthreads();
    float* ypOut = wrb ? p.yp1 : p.yp0;
    int r = tid >> 3;
    int d0 = (tid*4) & 31;
    f4 y4;
    #pragma unroll
    for (int e=0;e<4;e++){
      float acc = 0.f;
      #pragma unroll
      for (int c2=0;c2<HC;c2++) acc += hT[r][c2] * wlS[d0+e][c2];
      y4[e] = acc;
    }
    st16f_cg(ypOut + (size_t)((bi*GC + cj)*BM + r)*DIN + d0, y4);
  }

  grp_barrier(p.cnt + bi*NSTEP + g, (u32)GC, tid);
}

__global__ __launch_bounds__(256, 1) void persist(PP p){
  __shared__ u16 Ahi[BM][LDA];
  __shared__ u16 Alo[BM][LDA];
  __shared__ float gLds[4][BM][HC+1];
  __shared__ float hT[BM][HC+1];
  __shared__ float wlS[DIN][HC+1];

  const int tid = threadIdx.x;
  const int w   = tid >> 6;
  const int l   = tid & 63;
  const int bi  = (int)(blockIdx.x & 7);
  const int cj  = (int)(blockIdx.x >> 3);
  const int r0  = bi*BM;
  const int hc0 = cj*HC;
  const int l15 = l & 15;
  const int lk  = l >> 4;
  const int gcol = w*HH + hc0 + l15;

  // Wl slice -> LDS
  for (int i=tid; i<DIN*HC; i+=256){
    int d = i >> 4, c = i & 15;
    wlS[d][c] = p.Wl[(size_t)d*HH + hc0 + c];
  }
  float blv = (tid < DIN) ? p.bl[tid] : 0.f;

  float cre[2] = {0.f, 0.f};

  float bv[4][2];
  {
    int col0 = (tid*2) & 15;
    #pragma unroll
    for (int gq=0; gq<4; gq++){
      bv[gq][0] = p.bE[gq*HH + hc0 + col0];
      bv[gq][1] = p.bE[gq*HH + hc0 + col0 + 1];
    }
  }

  bh8 wh[16], wl[16];
  bh8 wxh = *(const bh8*)(p.WXhi + (size_t)gcol*DIN + lk*8);
  bh8 wxl = *(const bh8*)(p.WXlo + (size_t)gcol*DIN + lk*8);
  {
    const u16* a = p.WEhi + (size_t)gcol*HH;
    const u16* b = p.WElo + (size_t)gcol*HH;
    #pragma unroll
    for (int ks=0; ks<16; ks++){
      wh[ks] = *(const bh8*)(a + ks*32 + lk*8);
      wl[ks] = *(const bh8*)(b + ks*32 + lk*8);
    }
  }
  vm_wait0(); SB0();
  __syncthreads();

  for (int g=0; g<512; g++)
    dstep<0>(p, g, wh, wl, wxh, wxl, bv, blv, cre, Ahi, Alo, gLds, hT, wlS,
             tid, w, l15, lk, bi, cj, r0, hc0, gcol);

  // decoder step 0: stream raw Whh_d, bias = b_d
  {
    float bvD[4][2];
    int col0 = (tid*2) & 15;
    #pragma unroll
    for (int gq=0; gq<4; gq++){
      bvD[gq][0] = p.bD[gq*HH + hc0 + col0];
      bvD[gq][1] = p.bD[gq*HH + hc0 + col0 + 1];
    }
    vm_wait0(); SB0();
    dstep<1>(p, 512, wh, wl, wxh, wxl, bvD, blv, cre, Ahi, Alo, gLds, hT, wlS,
             tid, w, l15, lk, bi, cj, r0, hc0, gcol);
  }

  // load combined decoder weights + bias into registers
  {
    const u16* a = p.WChi + (size_t)gcol*HH;
    const u16* b = p.WClo + (size_t)gcol*HH;
    #pragma unroll
    for (int ks=0; ks<16; ks++){
      wh[ks] = *(const bh8*)(a + ks*32 + lk*8);
      wl[ks] = *(const bh8*)(b + ks*32 + lk*8);
    }
    int col0 = (tid*2) & 15;
    #pragma unroll
    for (int gq=0; gq<4; gq++){
      bv[gq][0] = p.bC[gq*HH + hc0 + col0];
      bv[gq][1] = p.bC[gq*HH + hc0 + col0 + 1];
    }
    vm_wait0(); SB0();
  }

  for (int g=513; g<1024; g++)
    dstep<2>(p, g, wh, wl, wxh, wxl, bv, blv, cre, Ahi, Alo, gLds, hT, wlS,
             tid, w, l15, lk, bi, cj, r0, hc0, gcol);

  // final y reduce (out[511]) from yp written at g=1023 (wrb=1 -> yp1)
  if (tid < DIN){
    const float* q = p.yp1 + (size_t)bi*(GC*BM*DIN) + (size_t)cj*DIN + tid;
    float t[GC];
    #pragma unroll
    for (int c2=0;c2<GC;c2++) t[c2] = ld4f_cg(q + (size_t)c2*(BM*DIN));
    vm_wait0(); SB0();
    float acc = blv;
    #pragma unroll
    for (int c2=0;c2<GC;c2++) acc += t[c2];
    st4f_nc(p.out + (size_t)511*(NB*DIN) + (size_t)(r0+cj)*DIN + tid, acc);
  }
}

// ---------------- host ----------------
extern "C" void kernel_launch(void* const* d_in, const int* in_sizes, int n_in,
                              void* d_out, int out_size, void* d_ws, size_t ws_size,
                              hipStream_t stream) {
  (void)in_sizes; (void)n_in; (void)out_size; (void)ws_size;
  const float* X    = (const float*)d_in[0];
  const float* WihE = (const float*)d_in[1];
  const float* WhhE = (const float*)d_in[2];
  const float* bE   = (const float*)d_in[3];
  const float* WihD = (const float*)d_in[4];
  const float* WhhD = (const float*)d_in[5];
  const float* bD   = (const float*)d_in[6];
  const float* Wl   = (const float*)d_in[7];
  const float* bl   = (const float*)d_in[8];
  float* out = (float*)d_out;

  char* p = (char*)d_ws;
  auto alloc = [&](size_t bytes)->char* {
    char* r = p; p += (bytes + 255) & ~(size_t)255; return r;
  };
  const size_t WN = (size_t)4*HH*HH;
  u16* WhhE_hi = (u16*)alloc(WN*2);
  u16* WhhE_lo = (u16*)alloc(WN*2);
  u16* WhhD_hi = (u16*)alloc(WN*2);
  u16* WhhD_lo = (u16*)alloc(WN*2);
  u16* Wc_hi   = (u16*)alloc(WN*2);
  u16* Wc_lo   = (u16*)alloc(WN*2);
  u16* WihE_hi = (u16*)alloc((size_t)4*HH*DIN*2);
  u16* WihE_lo = (u16*)alloc((size_t)4*HH*DIN*2);
  float* bcomb = (float*)alloc((size_t)4*HH*4);
  u16* hHi0 = (u16*)alloc((size_t)NB*HH*2);
  u16* hLo0 = (u16*)alloc((size_t)NB*HH*2);
  u16* hHi1 = (u16*)alloc((size_t)NB*HH*2);
  u16* hLo1 = (u16*)alloc((size_t)NB*HH*2);
  float* yp0 = (float*)alloc((size_t)GB*GC*BM*DIN*4);
  float* yp1 = (float*)alloc((size_t)GB*GC*BM*DIN*4);
  u32* cnt   = (u32*)alloc((size_t)GB*NSTEP*4);

  hipMemsetAsync(cnt,  0, (size_t)GB*NSTEP*4, stream);
  hipMemsetAsync(hHi1, 0, (size_t)NB*HH*2, stream);
  hipMemsetAsync(hLo1, 0, (size_t)NB*HH*2, stream);

  split_kernel<<<(int)((WN+255)/256), 256, 0, stream>>>(WhhE, WhhE_hi, WhhE_lo, (int)WN);
  split_kernel<<<(int)((WN+255)/256), 256, 0, stream>>>(WhhD, WhhD_hi, WhhD_lo, (int)WN);
  split_kernel<<<(4*HH*DIN+255)/256, 256, 0, stream>>>(WihE, WihE_hi, WihE_lo, 4*HH*DIN);
  comb_kernel<<<(int)((WN+255)/256), 256, 0, stream>>>(WhhD, WihD, Wl, Wc_hi, Wc_lo);
  bcomb_kernel<<<(4*HH+255)/256, 256, 0, stream>>>(bD, WihD, bl, bcomb);

  PP P;
  P.WEhi = WhhE_hi; P.WElo = WhhE_lo;
  P.WXhi = WihE_hi; P.WXlo = WihE_lo;
  P.bE = bE;
  P.WDhi = WhhD_hi; P.WDlo = WhhD_lo;
  P.bD = bD;
  P.WChi = Wc_hi; P.WClo = Wc_lo;
  P.bC = bcomb;
  P.X = X; P.Wl = Wl; P.bl = bl;
  P.hHi0 = hHi0; P.hLo0 = hLo0; P.hHi1 = hHi1; P.hLo1 = hLo1;
  P.yp0 = yp0; P.yp1 = yp1;
  P.out = out;
  P.cnt = cnt;

  persist<<<dim3(GB*GC), dim3(256), 0, stream>>>(P);
}